// Round 13
// baseline (167.859 us; speedup 1.0000x reference)
//
#include <hip/hip_runtime.h>
#include <hip/hip_bf16.h>
#include <stdint.h>

#define NROWS 8192
#define DIM   1024

typedef __attribute__((ext_vector_type(4))) int    i32x4;
typedef __attribute__((ext_vector_type(4))) float  f32x4;

// ---------------------------------------------------------------------------
// helpers
// ---------------------------------------------------------------------------
__device__ __forceinline__ unsigned int f32_key(float val) {
    unsigned int b = __float_as_uint(val);
    b ^= (unsigned int)(((int)b >> 31) | 0x80000000);  // monotone map
    return b;
}
__device__ __forceinline__ float key_val(unsigned long long k) {
    unsigned int b = (unsigned int)(k >> 32);
    b = (b & 0x80000000u) ? (b ^ 0x80000000u) : ~b;
    return __uint_as_float(b);
}
__device__ __forceinline__ void load_lds16(const void* g, void* l) {
    __builtin_amdgcn_global_load_lds((const __attribute__((address_space(1))) void*)g,
                                     (__attribute__((address_space(3))) void*)l, 16, 0, 0);
}

// ---------------------------------------------------------------------------
// prep: per-row sum-of-squares (fp64) + per-row max|x| + i8 quantization.
// ---------------------------------------------------------------------------
__global__ __launch_bounds__(256) void prep_i8_kernel(const float* __restrict__ A,
                                                      const float* __restrict__ B,
                                                      signed char* __restrict__ Aq,
                                                      signed char* __restrict__ Bq,
                                                      float* __restrict__ fA,
                                                      float* __restrict__ fB,
                                                      float* __restrict__ a2,
                                                      float* __restrict__ n2) {
    const float* src = blockIdx.y ? B : A;
    signed char* qdst = blockIdx.y ? Bq : Aq;
    float* fdst = blockIdx.y ? fB : fA;
    float* sdst = blockIdx.y ? n2 : a2;
    int row  = blockIdx.x * 4 + (threadIdx.x >> 6);
    int lane = threadIdx.x & 63;
    const float* p = src + (size_t)row * DIM;

    float4 v[4];
    double s = 0.0;
    float mx = 0.0f;
#pragma unroll
    for (int q = 0; q < 4; ++q) {
        v[q] = *reinterpret_cast<const float4*>(p + (size_t)(lane + 64 * q) * 4);
        s += (double)v[q].x * v[q].x + (double)v[q].y * v[q].y +
             (double)v[q].z * v[q].z + (double)v[q].w * v[q].w;
        mx = fmaxf(mx, fmaxf(fmaxf(fabsf(v[q].x), fabsf(v[q].y)),
                             fmaxf(fabsf(v[q].z), fabsf(v[q].w))));
    }
#pragma unroll
    for (int m = 32; m >= 1; m >>= 1) {
        s  += __shfl_xor(s, m, 64);
        mx  = fmaxf(mx, __shfl_xor(mx, m, 64));
    }
    mx = fmaxf(mx, 1e-30f);
    const float scale = 127.0f / mx;
#pragma unroll
    for (int q = 0; q < 4; ++q) {
        int q0 = (int)rintf(v[q].x * scale);
        int q1 = (int)rintf(v[q].y * scale);
        int q2 = (int)rintf(v[q].z * scale);
        int q3 = (int)rintf(v[q].w * scale);
        int packed = (q0 & 0xFF) | ((q1 & 0xFF) << 8) | ((q2 & 0xFF) << 16) | (q3 << 24);
        *reinterpret_cast<int*>(qdst + (size_t)row * DIM + (size_t)(lane + 64 * q) * 4) = packed;
    }
    if (lane == 0) { sdst[row] = (float)s; fdst[row] = mx / 127.0f; }
}

// ---------------------------------------------------------------------------
// i8 MFMA screening GEMM: r9 structure (BK=64 dbuf, one __syncthreads per
// K-tile) with ALL addressing hoisted out of the loop. Source pointers,
// LDS dst pointers, and ds_read byte-offsets are computed once; the 16
// K-tiles are hand-unrolled with literal +OFF constants (fold into load
// offset immediates) and statically-indexed buffers. Numerics, layout,
// swizzle (chunk = g ^ ((row>>1)&3), 0-conflict) identical to r9.
// dot = (float)acc * fA[row] * fB[col]  (|acc| <= 1024*127^2 < 2^24, exact).
// ---------------------------------------------------------------------------
__global__ __launch_bounds__(256, 4) void mfma_i8_kernel(
        const signed char* __restrict__ Aq,
        const signed char* __restrict__ Bq,
        const float* __restrict__ fA, const float* __restrict__ fB,
        const float* __restrict__ a2, const float* __restrict__ n2,
        unsigned long long* __restrict__ cand /* [NROWS][128][2] */) {
    __shared__ signed char lds[2][2][128 * 64];  // [buf][A/B][8 KB]

    const int tid  = threadIdx.x;
    const int w    = tid >> 6;
    const int lane = tid & 63;
    const int row0 = blockIdx.x * 128;
    const int col0 = blockIdx.y * 128;
    const int wr = w >> 1, wc = w & 1;
    const int g = lane >> 4, m = lane & 15;

    i32x4 acc[4][4];
#pragma unroll
    for (int r = 0; r < 4; ++r)
#pragma unroll
        for (int c = 0; c < 4; ++c) acc[r][c] = (i32x4)0;

    const signed char* gA = Aq + (size_t)row0 * DIM;
    const signed char* gB = Bq + (size_t)col0 * DIM;

    // ---- hoisted staging addresses (identical arithmetic to r9's stage) ----
    const int li0 = tid, li1 = 256 + tid;
    const int sr0 = li0 >> 2, sc0 = (li0 & 3) ^ ((sr0 >> 1) & 3);
    const int sr1 = li1 >> 2, sc1 = (li1 & 3) ^ ((sr1 >> 1) & 3);
    const signed char* srcA0 = gA + (size_t)sr0 * DIM + sc0 * 16;
    const signed char* srcA1 = gA + (size_t)sr1 * DIM + sc1 * 16;
    const signed char* srcB0 = gB + (size_t)sr0 * DIM + sc0 * 16;
    const signed char* srcB1 = gB + (size_t)sr1 * DIM + sc1 * 16;
    char* dA0b0 = (char*)&lds[0][0][0] + (size_t)li0 * 16;
    char* dA1b0 = (char*)&lds[0][0][0] + (size_t)li1 * 16;
    char* dB0b0 = (char*)&lds[0][1][0] + (size_t)li0 * 16;
    char* dB1b0 = (char*)&lds[0][1][0] + (size_t)li1 * 16;
    char* dA0b1 = (char*)&lds[1][0][0] + (size_t)li0 * 16;
    char* dA1b1 = (char*)&lds[1][0][0] + (size_t)li1 * 16;
    char* dB0b1 = (char*)&lds[1][1][0] + (size_t)li0 * 16;
    char* dB1b1 = (char*)&lds[1][1][0] + (size_t)li1 * 16;

#define STAGE0(OFF) { load_lds16(srcA0 + (OFF), dA0b0); load_lds16(srcA1 + (OFF), dA1b0); \
                      load_lds16(srcB0 + (OFF), dB0b0); load_lds16(srcB1 + (OFF), dB1b0); }
#define STAGE1(OFF) { load_lds16(srcA0 + (OFF), dA0b1); load_lds16(srcA1 + (OFF), dA1b1); \
                      load_lds16(srcB0 + (OFF), dB0b1); load_lds16(srcB1 + (OFF), dB1b1); }

    // ---- hoisted ds_read byte offsets (identical arithmetic to r9) ----
    int offA[4], offB[4];
#pragma unroll
    for (int r = 0; r < 4; ++r) {
        int arow = wr * 64 + r * 16 + m;
        offA[r] = arow * 64 + (g ^ ((arow >> 1) & 3)) * 16;
        int brow = wc * 64 + r * 16 + m;
        offB[r] = brow * 64 + (g ^ ((brow >> 1) & 3)) * 16;
    }
    const char* laB0 = (const char*)&lds[0][0][0];
    const char* lbB0 = (const char*)&lds[0][1][0];
    const char* laB1 = (const char*)&lds[1][0][0];
    const char* lbB1 = (const char*)&lds[1][1][0];

    auto compute = [&](const char* la, const char* lb) {
        i32x4 af[4], bf[4];
#pragma unroll
        for (int r = 0; r < 4; ++r) {
            af[r] = *(const i32x4*)(la + offA[r]);
            bf[r] = *(const i32x4*)(lb + offB[r]);
        }
#pragma unroll
        for (int r = 0; r < 4; ++r)
#pragma unroll
            for (int c = 0; c < 4; ++c)
                acc[r][c] = __builtin_amdgcn_mfma_i32_16x16x64_i8(af[r], bf[c], acc[r][c], 0, 0, 0);
    };

    // ---- hand-unrolled 16-tile pipeline (stage t+1 while computing t) ----
    STAGE0(0);   __syncthreads();
    STAGE1(64);  compute(laB0, lbB0); __syncthreads();
    STAGE0(128); compute(laB1, lbB1); __syncthreads();
    STAGE1(192); compute(laB0, lbB0); __syncthreads();
    STAGE0(256); compute(laB1, lbB1); __syncthreads();
    STAGE1(320); compute(laB0, lbB0); __syncthreads();
    STAGE0(384); compute(laB1, lbB1); __syncthreads();
    STAGE1(448); compute(laB0, lbB0); __syncthreads();
    STAGE0(512); compute(laB1, lbB1); __syncthreads();
    STAGE1(576); compute(laB0, lbB0); __syncthreads();
    STAGE0(640); compute(laB1, lbB1); __syncthreads();
    STAGE1(704); compute(laB0, lbB0); __syncthreads();
    STAGE0(768); compute(laB1, lbB1); __syncthreads();
    STAGE1(832); compute(laB0, lbB0); __syncthreads();
    STAGE0(896); compute(laB1, lbB1); __syncthreads();
    STAGE1(960); compute(laB0, lbB0); __syncthreads();
    compute(laB1, lbB1);
#undef STAGE0
#undef STAGE1

    // ---- epilogue: dequant, reference-order val, per-row top-2 per strip ----
    const int colbase = col0 + wc * 64;
    const int cb = blockIdx.y * 2 + wc;
    float n2v[4], fbv[4];
#pragma unroll
    for (int c = 0; c < 4; ++c) {
        n2v[c] = n2[colbase + c * 16 + m];
        fbv[c] = fB[colbase + c * 16 + m];
    }
#pragma unroll
    for (int r = 0; r < 4; ++r) {
#pragma unroll
        for (int j = 0; j < 4; ++j) {
            int row = row0 + wr * 64 + r * 16 + g * 4 + j;
            float arow = a2[row];
            float far  = fA[row];
            unsigned long long k1 = 0ull, k2 = 0ull;
#pragma unroll
            for (int c = 0; c < 4; ++c) {
                int col = colbase + c * 16 + m;
                float dot = (float)acc[r][c][j] * far * fbv[c];
                float t = arow + n2v[c];
                t = t - 2.0f * dot;
                float val = t * (1.0f / 1024.0f);
                unsigned long long key =
                    ((unsigned long long)f32_key(val) << 32) |
                    (unsigned long long)(0xFFFFFFFFu - (unsigned)col);
                if (key > k1) { k2 = k1; k1 = key; } else if (key > k2) { k2 = key; }
            }
#pragma unroll
            for (int s = 1; s < 16; s <<= 1) {
                unsigned long long o1 = __shfl_xor(k1, s, 64);
                unsigned long long o2 = __shfl_xor(k2, s, 64);
                unsigned long long hi = k1 > o1 ? k1 : o1;
                unsigned long long md = k1 > o1 ? o1 : k1;
                unsigned long long l2 = k2 > o2 ? k2 : o2;
                k1 = hi; k2 = md > l2 ? md : l2;
            }
            if (m == 0) {
                unsigned long long* p = &cand[((size_t)row * 128 + cb) * 2];
                p[0] = k1; p[1] = k2;
            }
        }
    }
}

// ---------------------------------------------------------------------------
// fused refine+gather, wave-parallel fp64 recompute of candidates within
// DELTA; winner's negative row copied straight to out. Lowest-index tiebreak.
// ---------------------------------------------------------------------------
#define DELTA 1.5e-2f
__global__ __launch_bounds__(256) void refine_gather_kernel(
        const float* __restrict__ A, const float* __restrict__ B,
        const float* __restrict__ a2, const float* __restrict__ n2,
        const unsigned long long* __restrict__ cand,
        float* __restrict__ out) {
    int row  = blockIdx.x * 4 + (threadIdx.x >> 6);
    int lane = threadIdx.x & 63;
    const unsigned long long* cp = cand + (size_t)row * 256;

    unsigned long long k[4];
#pragma unroll
    for (int q = 0; q < 4; ++q) k[q] = cp[lane + 64 * q];

    unsigned long long mx = k[0];
#pragma unroll
    for (int q = 1; q < 4; ++q) if (k[q] > mx) mx = k[q];
#pragma unroll
    for (int s = 1; s < 64; s <<= 1) {
        unsigned long long o = __shfl_xor(mx, s, 64);
        if (o > mx) mx = o;
    }
    const float thr = key_val(mx) - DELTA;

    const float* ap = A + (size_t)row * DIM;
    const double a2row = (double)a2[row];
    double bestv = -1.0e300;
    int    bestc = 0x7FFFFFFF;

#pragma unroll
    for (int q = 0; q < 4; ++q) {
        float kv = key_val(k[q]);
        int   kc = (int)(0xFFFFFFFFu - (unsigned int)(k[q] & 0xFFFFFFFFull));
        unsigned long long mask = __ballot(kv >= thr);
        while (mask) {
            int src = __ffsll((long long)mask) - 1;
            mask &= mask - 1;
            int col = __shfl(kc, src, 64);
            const float* bp = B + (size_t)col * DIM;
            double part = 0.0;
#pragma unroll
            for (int u = 0; u < 4; ++u) {
                float4 va = reinterpret_cast<const float4*>(ap)[lane + 64 * u];
                float4 vb = reinterpret_cast<const float4*>(bp)[lane + 64 * u];
                part += (double)va.x * vb.x + (double)va.y * vb.y +
                        (double)va.z * vb.z + (double)va.w * vb.w;
            }
#pragma unroll
            for (int s = 1; s < 64; s <<= 1) part += __shfl_xor(part, s, 64);
            double val = (a2row + (double)n2[col] - 2.0 * part) * (1.0 / 1024.0);
            if (val > bestv || (val == bestv && col < bestc)) { bestv = val; bestc = col; }
        }
    }

    const float4* srcp = reinterpret_cast<const float4*>(B + (size_t)bestc * DIM);
    float4*       dstp = reinterpret_cast<float4*>(out + (size_t)row * DIM);
#pragma unroll
    for (int u = 0; u < 4; ++u) dstp[lane + 64 * u] = srcp[lane + 64 * u];
}

// ---------------------------------------------------------------------------
// fallback path (round-1, proven correct) if ws is too small
// ---------------------------------------------------------------------------
__global__ __launch_bounds__(256) void sumsq_kernel(const float* __restrict__ A,
                                                    const float* __restrict__ B,
                                                    float* __restrict__ a2,
                                                    float* __restrict__ n2) {
    const float* src = (blockIdx.y == 0) ? A : B;
    float*       dst = (blockIdx.y == 0) ? a2 : n2;
    int row  = blockIdx.x * 4 + (threadIdx.x >> 6);
    int lane = threadIdx.x & 63;
    const float* p = src + (size_t)row * DIM;
    double s = 0.0;
#pragma unroll
    for (int q = 0; q < 4; ++q) {
        float4 v = *reinterpret_cast<const float4*>(p + (size_t)(lane + 64 * q) * 4);
        s += (double)v.x * v.x + (double)v.y * v.y + (double)v.z * v.z + (double)v.w * v.w;
    }
#pragma unroll
    for (int m = 32; m >= 1; m >>= 1) s += __shfl_xor(s, m, 64);
    if (lane == 0) dst[row] = (float)s;
}

__global__ __launch_bounds__(256) void mse_argmax_kernel(
        const float* __restrict__ A, const float* __restrict__ B,
        const float* __restrict__ a2, const float* __restrict__ n2,
        unsigned long long* __restrict__ best) {
    __shared__ float As[16][132];
    __shared__ float Bs[16][132];
    const int tid = threadIdx.x;
    const int tx = tid & 15, ty = tid >> 4;
    const int row0 = blockIdx.x * 128;
    const int col0 = blockIdx.y * 128;
    float acc[8][8];
#pragma unroll
    for (int r = 0; r < 8; ++r)
#pragma unroll
        for (int c = 0; c < 8; ++c) acc[r][c] = 0.0f;
    for (int kt = 0; kt < DIM; kt += 16) {
#pragma unroll
        for (int p = 0; p < 2; ++p) {
            int li = p * 256 + tid;
            int r  = li >> 2;
            int s4 = li & 3;
            float4 va = *reinterpret_cast<const float4*>(&A[(size_t)(row0 + r) * DIM + kt + s4 * 4]);
            float4 vb = *reinterpret_cast<const float4*>(&B[(size_t)(col0 + r) * DIM + kt + s4 * 4]);
            As[s4 * 4 + 0][r] = va.x; As[s4 * 4 + 1][r] = va.y;
            As[s4 * 4 + 2][r] = va.z; As[s4 * 4 + 3][r] = va.w;
            Bs[s4 * 4 + 0][r] = vb.x; Bs[s4 * 4 + 1][r] = vb.y;
            Bs[s4 * 4 + 2][r] = vb.z; Bs[s4 * 4 + 3][r] = vb.w;
        }
        __syncthreads();
#pragma unroll
        for (int kk = 0; kk < 16; ++kk) {
            float af[8], bfv[8];
#pragma unroll
            for (int r = 0; r < 8; ++r) af[r] = As[kk][ty + 16 * r];
#pragma unroll
            for (int c = 0; c < 8; ++c) bfv[c] = Bs[kk][tx + 16 * c];
#pragma unroll
            for (int r = 0; r < 8; ++r)
#pragma unroll
                for (int c = 0; c < 8; ++c) acc[r][c] = fmaf(af[r], bfv[c], acc[r][c]);
        }
        __syncthreads();
    }
#pragma unroll
    for (int r = 0; r < 8; ++r) {
        const int row = row0 + ty + 16 * r;
        const float arow = a2[row];
        unsigned long long bestk = 0ull;
#pragma unroll
        for (int c = 0; c < 8; ++c) {
            const int col = col0 + tx + 16 * c;
            float t = arow + n2[col];
            t = t - 2.0f * acc[r][c];
            const float val = t * (1.0f / 1024.0f);
            unsigned long long key =
                ((unsigned long long)f32_key(val) << 32) |
                (unsigned long long)(0xFFFFFFFFu - (unsigned)col);
            if (key > bestk) bestk = key;
        }
#pragma unroll
        for (int mm = 1; mm < 16; mm <<= 1) {
            unsigned long long other = __shfl_xor(bestk, mm, 16);
            if (other > bestk) bestk = other;
        }
        if (tx == 0) atomicMax(&best[row], bestk);
    }
}

__global__ __launch_bounds__(256) void gather_kernel(
        const float* __restrict__ B,
        const unsigned long long* __restrict__ best,
        float* __restrict__ out) {
    const int row = blockIdx.x;
    const unsigned int col = 0xFFFFFFFFu - (unsigned int)(best[row] & 0xFFFFFFFFull);
    const float4* src = reinterpret_cast<const float4*>(B + (size_t)col * DIM);
    float4*       dst = reinterpret_cast<float4*>(out + (size_t)row * DIM);
    dst[threadIdx.x] = src[threadIdx.x];
}

// ---------------------------------------------------------------------------
extern "C" void kernel_launch(void* const* d_in, const int* in_sizes, int n_in,
                              void* d_out, int out_size, void* d_ws, size_t ws_size,
                              hipStream_t stream) {
    const float* anchor   = (const float*)d_in[0];
    const float* negative = (const float*)d_in[1];
    float* out = (float*)d_out;
    char* ws = (char*)d_ws;

    const size_t qplane    = (size_t)NROWS * DIM;                                // 8 MB
    const size_t candBytes = (size_t)NROWS * 256 * sizeof(unsigned long long);   // 16 MB
    const size_t SC        = 32768;                                              // 8192 floats
    const size_t need_i8   = 2 * qplane + 4 * SC + candBytes;                    // ~32.1 MB

    if (ws_size >= need_i8) {
        signed char* Aq = (signed char*)(ws);
        signed char* Bq = (signed char*)(ws + qplane);
        float* fA = (float*)(ws + 2 * qplane);
        float* fB = (float*)(ws + 2 * qplane + SC);
        float* a2 = (float*)(ws + 2 * qplane + 2 * SC);
        float* n2 = (float*)(ws + 2 * qplane + 3 * SC);
        unsigned long long* cand = (unsigned long long*)(ws + 2 * qplane + 4 * SC);

        prep_i8_kernel<<<dim3(NROWS / 4, 2), 256, 0, stream>>>(
            anchor, negative, Aq, Bq, fA, fB, a2, n2);
        mfma_i8_kernel<<<dim3(NROWS / 128, NROWS / 128), 256, 0, stream>>>(
            Aq, Bq, fA, fB, a2, n2, cand);
        refine_gather_kernel<<<NROWS / 4, 256, 0, stream>>>(
            anchor, negative, a2, n2, cand, out);
    } else {
        // --- round-1 fallback (proven correct, needs 128 KB) ---
        float* a2 = (float*)(ws);
        float* n2 = (float*)(ws + 32768);
        unsigned long long* best = (unsigned long long*)(ws + 65536);
        hipMemsetAsync(best, 0, NROWS * sizeof(unsigned long long), stream);
        sumsq_kernel<<<dim3(NROWS / 4, 2), 256, 0, stream>>>(anchor, negative, a2, n2);
        mse_argmax_kernel<<<dim3(NROWS / 128, NROWS / 128), 256, 0, stream>>>(anchor, negative, a2, n2, best);
        gather_kernel<<<NROWS, 256, 0, stream>>>(negative, best, out);
    }
}

// Round 14
// 162.767 us; speedup vs baseline: 1.0313x; 1.0313x over previous
//
#include <hip/hip_runtime.h>
#include <hip/hip_bf16.h>
#include <stdint.h>

#define NROWS 8192
#define DIM   1024

typedef __attribute__((ext_vector_type(4))) int    i32x4;
typedef __attribute__((ext_vector_type(4))) float  f32x4;

// ---------------------------------------------------------------------------
// helpers
// ---------------------------------------------------------------------------
__device__ __forceinline__ unsigned int f32_key(float val) {
    unsigned int b = __float_as_uint(val);
    b ^= (unsigned int)(((int)b >> 31) | 0x80000000);  // monotone map
    return b;
}
__device__ __forceinline__ float key_val(unsigned long long k) {
    unsigned int b = (unsigned int)(k >> 32);
    b = (b & 0x80000000u) ? (b ^ 0x80000000u) : ~b;
    return __uint_as_float(b);
}
__device__ __forceinline__ void load_lds16(const void* g, void* l) {
    __builtin_amdgcn_global_load_lds((const __attribute__((address_space(1))) void*)g,
                                     (__attribute__((address_space(3))) void*)l, 16, 0, 0);
}

// ---------------------------------------------------------------------------
// prep: per-row sum-of-squares (fp64) + per-row max|x| + i8 quantization.
// One wave per row. q = rint(x * 127/rowmax)  (|x| <= rowmax -> no clipping).
// Stores dequant factor f[row] = rowmax/127.
// ---------------------------------------------------------------------------
__global__ __launch_bounds__(256) void prep_i8_kernel(const float* __restrict__ A,
                                                      const float* __restrict__ B,
                                                      signed char* __restrict__ Aq,
                                                      signed char* __restrict__ Bq,
                                                      float* __restrict__ fA,
                                                      float* __restrict__ fB,
                                                      float* __restrict__ a2,
                                                      float* __restrict__ n2) {
    const float* src = blockIdx.y ? B : A;
    signed char* qdst = blockIdx.y ? Bq : Aq;
    float* fdst = blockIdx.y ? fB : fA;
    float* sdst = blockIdx.y ? n2 : a2;
    int row  = blockIdx.x * 4 + (threadIdx.x >> 6);
    int lane = threadIdx.x & 63;
    const float* p = src + (size_t)row * DIM;

    float4 v[4];
    double s = 0.0;
    float mx = 0.0f;
#pragma unroll
    for (int q = 0; q < 4; ++q) {
        v[q] = *reinterpret_cast<const float4*>(p + (size_t)(lane + 64 * q) * 4);
        s += (double)v[q].x * v[q].x + (double)v[q].y * v[q].y +
             (double)v[q].z * v[q].z + (double)v[q].w * v[q].w;
        mx = fmaxf(mx, fmaxf(fmaxf(fabsf(v[q].x), fabsf(v[q].y)),
                             fmaxf(fabsf(v[q].z), fabsf(v[q].w))));
    }
#pragma unroll
    for (int m = 32; m >= 1; m >>= 1) {
        s  += __shfl_xor(s, m, 64);
        mx  = fmaxf(mx, __shfl_xor(mx, m, 64));
    }
    mx = fmaxf(mx, 1e-30f);
    const float scale = 127.0f / mx;
#pragma unroll
    for (int q = 0; q < 4; ++q) {
        int q0 = (int)rintf(v[q].x * scale);
        int q1 = (int)rintf(v[q].y * scale);
        int q2 = (int)rintf(v[q].z * scale);
        int q3 = (int)rintf(v[q].w * scale);
        int packed = (q0 & 0xFF) | ((q1 & 0xFF) << 8) | ((q2 & 0xFF) << 16) | (q3 << 24);
        *reinterpret_cast<int*>(qdst + (size_t)row * DIM + (size_t)(lane + 64 * q) * 4) = packed;
    }
    if (lane == 0) { sdst[row] = (float)s; fdst[row] = mx / 127.0f; }
}

// ---------------------------------------------------------------------------
// i8 MFMA screening GEMM, double-buffered (r9/r12, best measured total):
// prologue STAGE(0); per iter: issue STAGE(t+1, buf^1) -> ds_read+MFMA from
// buf -> __syncthreads. Stage latency overlaps the compute phase; one
// barrier per K-tile. BK=64, dbuf LDS = 32 KB -> 4 blocks/CU co-resident.
// Swizzle chunk = g ^ ((row>>1)&3) (0-conflict, verified r4/r5/r8/r9).
// dot = (float)acc * fA[row] * fB[col]  (|acc| <= 1024*127^2 < 2^24, exact).
// ---------------------------------------------------------------------------
__global__ __launch_bounds__(256, 4) void mfma_i8_kernel(
        const signed char* __restrict__ Aq,
        const signed char* __restrict__ Bq,
        const float* __restrict__ fA, const float* __restrict__ fB,
        const float* __restrict__ a2, const float* __restrict__ n2,
        unsigned long long* __restrict__ cand /* [NROWS][128][2] */) {
    __shared__ signed char lds[2][2][128 * 64];  // [buf][A/B][8 KB]

    const int tid  = threadIdx.x;
    const int w    = tid >> 6;
    const int lane = tid & 63;
    const int row0 = blockIdx.x * 128;
    const int col0 = blockIdx.y * 128;
    const int wr = w >> 1, wc = w & 1;
    const int g = lane >> 4, m = lane & 15;

    i32x4 acc[4][4];
#pragma unroll
    for (int r = 0; r < 4; ++r)
#pragma unroll
        for (int c = 0; c < 4; ++c) acc[r][c] = (i32x4)0;

    const signed char* gA = Aq + (size_t)row0 * DIM;
    const signed char* gB = Bq + (size_t)col0 * DIM;

    // stage K-tile starting at column kt into buffer buf.
    auto stage = [&](int kt, int buf) {
#pragma unroll
        for (int p = 0; p < 2; ++p) {
            int li  = p * 256 + tid;          // 0..511
            int row = li >> 2;                // 0..127
            int ck  = li & 3;                 // LDS 16B-chunk slot
            int cg  = ck ^ ((row >> 1) & 3);  // pre-swizzled source chunk
            load_lds16(gA + (size_t)row * DIM + kt + cg * 16,
                       (char*)&lds[buf][0][0] + (size_t)li * 16);
            load_lds16(gB + (size_t)row * DIM + kt + cg * 16,
                       (char*)&lds[buf][1][0] + (size_t)li * 16);
        }
    };

    stage(0, 0);
    __syncthreads();          // buf 0 ready

    int cur = 0;
    for (int t = 0; t < 16; ++t) {
        if (t < 15) stage((t + 1) * 64, cur ^ 1);   // loads fly during compute

        const signed char* la = &lds[cur][0][0];
        const signed char* lb = &lds[cur][1][0];
        i32x4 af[4], bf[4];
#pragma unroll
        for (int r = 0; r < 4; ++r) {
            int arow = wr * 64 + r * 16 + m;
            int ch   = g ^ ((arow >> 1) & 3);
            af[r] = *(const i32x4*)((const char*)la + arow * 64 + ch * 16);
            int brow = wc * 64 + r * 16 + m;
            int ch2  = g ^ ((brow >> 1) & 3);
            bf[r] = *(const i32x4*)((const char*)lb + brow * 64 + ch2 * 16);
        }
#pragma unroll
        for (int r = 0; r < 4; ++r)
#pragma unroll
            for (int c = 0; c < 4; ++c)
                acc[r][c] = __builtin_amdgcn_mfma_i32_16x16x64_i8(af[r], bf[c], acc[r][c], 0, 0, 0);

        __syncthreads();      // drains vmcnt(0): stage(t+1) landed; readers done
        cur ^= 1;
    }

    // ---- epilogue: dequant, reference-order val, per-row top-2 per strip ----
    const int colbase = col0 + wc * 64;
    const int cb = blockIdx.y * 2 + wc;
    float n2v[4], fbv[4];
#pragma unroll
    for (int c = 0; c < 4; ++c) {
        n2v[c] = n2[colbase + c * 16 + m];
        fbv[c] = fB[colbase + c * 16 + m];
    }
#pragma unroll
    for (int r = 0; r < 4; ++r) {
#pragma unroll
        for (int j = 0; j < 4; ++j) {
            int row = row0 + wr * 64 + r * 16 + g * 4 + j;
            float arow = a2[row];
            float far  = fA[row];
            unsigned long long k1 = 0ull, k2 = 0ull;
#pragma unroll
            for (int c = 0; c < 4; ++c) {
                int col = colbase + c * 16 + m;
                float dot = (float)acc[r][c][j] * far * fbv[c];
                float t = arow + n2v[c];
                t = t - 2.0f * dot;
                float val = t * (1.0f / 1024.0f);
                unsigned long long key =
                    ((unsigned long long)f32_key(val) << 32) |
                    (unsigned long long)(0xFFFFFFFFu - (unsigned)col);
                if (key > k1) { k2 = k1; k1 = key; } else if (key > k2) { k2 = key; }
            }
#pragma unroll
            for (int s = 1; s < 16; s <<= 1) {
                unsigned long long o1 = __shfl_xor(k1, s, 64);
                unsigned long long o2 = __shfl_xor(k2, s, 64);
                unsigned long long hi = k1 > o1 ? k1 : o1;
                unsigned long long md = k1 > o1 ? o1 : k1;
                unsigned long long l2 = k2 > o2 ? k2 : o2;
                k1 = hi; k2 = md > l2 ? md : l2;
            }
            if (m == 0) {
                unsigned long long* p = &cand[((size_t)row * 128 + cb) * 2];
                p[0] = k1; p[1] = k2;
            }
        }
    }
}

// ---------------------------------------------------------------------------
// fused refine+gather, wave-parallel: per row, approx-max over 256 keys;
// every candidate within DELTA is recomputed by the WHOLE WAVE (fp64
// partials + shuffle reduce, error ~1e-13 << any top-2 gap); winner's
// negative row is copied straight to out. Lowest-index tiebreak.
// ---------------------------------------------------------------------------
#define DELTA 1.5e-2f
__global__ __launch_bounds__(256) void refine_gather_kernel(
        const float* __restrict__ A, const float* __restrict__ B,
        const float* __restrict__ a2, const float* __restrict__ n2,
        const unsigned long long* __restrict__ cand,
        float* __restrict__ out) {
    int row  = blockIdx.x * 4 + (threadIdx.x >> 6);
    int lane = threadIdx.x & 63;
    const unsigned long long* cp = cand + (size_t)row * 256;

    unsigned long long k[4];
#pragma unroll
    for (int q = 0; q < 4; ++q) k[q] = cp[lane + 64 * q];

    unsigned long long mx = k[0];
#pragma unroll
    for (int q = 1; q < 4; ++q) if (k[q] > mx) mx = k[q];
#pragma unroll
    for (int s = 1; s < 64; s <<= 1) {
        unsigned long long o = __shfl_xor(mx, s, 64);
        if (o > mx) mx = o;
    }
    const float thr = key_val(mx) - DELTA;

    const float* ap = A + (size_t)row * DIM;
    const double a2row = (double)a2[row];
    double bestv = -1.0e300;
    int    bestc = 0x7FFFFFFF;

#pragma unroll
    for (int q = 0; q < 4; ++q) {
        float kv = key_val(k[q]);
        int   kc = (int)(0xFFFFFFFFu - (unsigned int)(k[q] & 0xFFFFFFFFull));
        unsigned long long mask = __ballot(kv >= thr);
        while (mask) {
            int src = __ffsll((long long)mask) - 1;
            mask &= mask - 1;
            int col = __shfl(kc, src, 64);
            const float* bp = B + (size_t)col * DIM;
            double part = 0.0;
#pragma unroll
            for (int u = 0; u < 4; ++u) {
                float4 va = reinterpret_cast<const float4*>(ap)[lane + 64 * u];
                float4 vb = reinterpret_cast<const float4*>(bp)[lane + 64 * u];
                part += (double)va.x * vb.x + (double)va.y * vb.y +
                        (double)va.z * vb.z + (double)va.w * vb.w;
            }
#pragma unroll
            for (int s = 1; s < 64; s <<= 1) part += __shfl_xor(part, s, 64);
            double val = (a2row + (double)n2[col] - 2.0 * part) * (1.0 / 1024.0);
            if (val > bestv || (val == bestv && col < bestc)) { bestv = val; bestc = col; }
        }
    }

    const float4* srcp = reinterpret_cast<const float4*>(B + (size_t)bestc * DIM);
    float4*       dstp = reinterpret_cast<float4*>(out + (size_t)row * DIM);
#pragma unroll
    for (int u = 0; u < 4; ++u) dstp[lane + 64 * u] = srcp[lane + 64 * u];
}

// ---------------------------------------------------------------------------
// fallback path (round-1, proven correct) if ws is too small
// ---------------------------------------------------------------------------
__global__ __launch_bounds__(256) void sumsq_kernel(const float* __restrict__ A,
                                                    const float* __restrict__ B,
                                                    float* __restrict__ a2,
                                                    float* __restrict__ n2) {
    const float* src = (blockIdx.y == 0) ? A : B;
    float*       dst = (blockIdx.y == 0) ? a2 : n2;
    int row  = blockIdx.x * 4 + (threadIdx.x >> 6);
    int lane = threadIdx.x & 63;
    const float* p = src + (size_t)row * DIM;
    double s = 0.0;
#pragma unroll
    for (int q = 0; q < 4; ++q) {
        float4 v = *reinterpret_cast<const float4*>(p + (size_t)(lane + 64 * q) * 4);
        s += (double)v.x * v.x + (double)v.y * v.y + (double)v.z * v.z + (double)v.w * v.w;
    }
#pragma unroll
    for (int m = 32; m >= 1; m >>= 1) s += __shfl_xor(s, m, 64);
    if (lane == 0) dst[row] = (float)s;
}

__global__ __launch_bounds__(256) void mse_argmax_kernel(
        const float* __restrict__ A, const float* __restrict__ B,
        const float* __restrict__ a2, const float* __restrict__ n2,
        unsigned long long* __restrict__ best) {
    __shared__ float As[16][132];
    __shared__ float Bs[16][132];
    const int tid = threadIdx.x;
    const int tx = tid & 15, ty = tid >> 4;
    const int row0 = blockIdx.x * 128;
    const int col0 = blockIdx.y * 128;
    float acc[8][8];
#pragma unroll
    for (int r = 0; r < 8; ++r)
#pragma unroll
        for (int c = 0; c < 8; ++c) acc[r][c] = 0.0f;
    for (int kt = 0; kt < DIM; kt += 16) {
#pragma unroll
        for (int p = 0; p < 2; ++p) {
            int li = p * 256 + tid;
            int r  = li >> 2;
            int s4 = li & 3;
            float4 va = *reinterpret_cast<const float4*>(&A[(size_t)(row0 + r) * DIM + kt + s4 * 4]);
            float4 vb = *reinterpret_cast<const float4*>(&B[(size_t)(col0 + r) * DIM + kt + s4 * 4]);
            As[s4 * 4 + 0][r] = va.x; As[s4 * 4 + 1][r] = va.y;
            As[s4 * 4 + 2][r] = va.z; As[s4 * 4 + 3][r] = va.w;
            Bs[s4 * 4 + 0][r] = vb.x; Bs[s4 * 4 + 1][r] = vb.y;
            Bs[s4 * 4 + 2][r] = vb.z; Bs[s4 * 4 + 3][r] = vb.w;
        }
        __syncthreads();
#pragma unroll
        for (int kk = 0; kk < 16; ++kk) {
            float af[8], bfv[8];
#pragma unroll
            for (int r = 0; r < 8; ++r) af[r] = As[kk][ty + 16 * r];
#pragma unroll
            for (int c = 0; c < 8; ++c) bfv[c] = Bs[kk][tx + 16 * c];
#pragma unroll
            for (int r = 0; r < 8; ++r)
#pragma unroll
                for (int c = 0; c < 8; ++c) acc[r][c] = fmaf(af[r], bfv[c], acc[r][c]);
        }
        __syncthreads();
    }
#pragma unroll
    for (int r = 0; r < 8; ++r) {
        const int row = row0 + ty + 16 * r;
        const float arow = a2[row];
        unsigned long long bestk = 0ull;
#pragma unroll
        for (int c = 0; c < 8; ++c) {
            const int col = col0 + tx + 16 * c;
            float t = arow + n2[col];
            t = t - 2.0f * acc[r][c];
            const float val = t * (1.0f / 1024.0f);
            unsigned long long key =
                ((unsigned long long)f32_key(val) << 32) |
                (unsigned long long)(0xFFFFFFFFu - (unsigned)col);
            if (key > bestk) bestk = key;
        }
#pragma unroll
        for (int mm = 1; mm < 16; mm <<= 1) {
            unsigned long long other = __shfl_xor(bestk, mm, 16);
            if (other > bestk) bestk = other;
        }
        if (tx == 0) atomicMax(&best[row], bestk);
    }
}

__global__ __launch_bounds__(256) void gather_kernel(
        const float* __restrict__ B,
        const unsigned long long* __restrict__ best,
        float* __restrict__ out) {
    const int row = blockIdx.x;
    const unsigned int col = 0xFFFFFFFFu - (unsigned int)(best[row] & 0xFFFFFFFFull);
    const float4* src = reinterpret_cast<const float4*>(B + (size_t)col * DIM);
    float4*       dst = reinterpret_cast<float4*>(out + (size_t)row * DIM);
    dst[threadIdx.x] = src[threadIdx.x];
}

// ---------------------------------------------------------------------------
extern "C" void kernel_launch(void* const* d_in, const int* in_sizes, int n_in,
                              void* d_out, int out_size, void* d_ws, size_t ws_size,
                              hipStream_t stream) {
    const float* anchor   = (const float*)d_in[0];
    const float* negative = (const float*)d_in[1];
    float* out = (float*)d_out;
    char* ws = (char*)d_ws;

    const size_t qplane    = (size_t)NROWS * DIM;                                // 8 MB
    const size_t candBytes = (size_t)NROWS * 256 * sizeof(unsigned long long);   // 16 MB
    const size_t SC        = 32768;                                              // 8192 floats
    const size_t need_i8   = 2 * qplane + 4 * SC + candBytes;                    // ~32.1 MB

    if (ws_size >= need_i8) {
        signed char* Aq = (signed char*)(ws);
        signed char* Bq = (signed char*)(ws + qplane);
        float* fA = (float*)(ws + 2 * qplane);
        float* fB = (float*)(ws + 2 * qplane + SC);
        float* a2 = (float*)(ws + 2 * qplane + 2 * SC);
        float* n2 = (float*)(ws + 2 * qplane + 3 * SC);
        unsigned long long* cand = (unsigned long long*)(ws + 2 * qplane + 4 * SC);

        prep_i8_kernel<<<dim3(NROWS / 4, 2), 256, 0, stream>>>(
            anchor, negative, Aq, Bq, fA, fB, a2, n2);
        mfma_i8_kernel<<<dim3(NROWS / 128, NROWS / 128), 256, 0, stream>>>(
            Aq, Bq, fA, fB, a2, n2, cand);
        refine_gather_kernel<<<NROWS / 4, 256, 0, stream>>>(
            anchor, negative, a2, n2, cand, out);
    } else {
        // --- round-1 fallback (proven correct, needs 128 KB) ---
        float* a2 = (float*)(ws);
        float* n2 = (float*)(ws + 32768);
        unsigned long long* best = (unsigned long long*)(ws + 65536);
        hipMemsetAsync(best, 0, NROWS * sizeof(unsigned long long), stream);
        sumsq_kernel<<<dim3(NROWS / 4, 2), 256, 0, stream>>>(anchor, negative, a2, n2);
        mse_argmax_kernel<<<dim3(NROWS / 128, NROWS / 128), 256, 0, stream>>>(anchor, negative, a2, n2, best);
        gather_kernel<<<NROWS, 256, 0, stream>>>(negative, best, out);
    }
}